// Round 1
// 880.016 us; speedup vs baseline: 1.0800x; 1.0800x over previous
//
#include <hip/hip_runtime.h>
#include <hip/hip_bf16.h>
#include <cmath>

#define AS_GLOBAL __attribute__((address_space(1)))
#define AS_LDS    __attribute__((address_space(3)))

typedef __attribute__((ext_vector_type(8))) short bf16x8;
typedef __attribute__((ext_vector_type(4))) float f32x4;
typedef unsigned short u16;

__device__ __forceinline__ u16 f2bf(float f) {
  union { __hip_bfloat16 h; u16 u; } cv;
  cv.h = __float2bfloat16(f);
  return cv.u;
}
__device__ __forceinline__ float bf2f(u16 u) {
  union { unsigned u32; float f; } v;
  v.u32 = ((unsigned)u) << 16;
  return v.f;
}

// ---------------------------------------------------------------- prep kernels

__global__ void k_f32_to_bf16(const float* __restrict__ in, u16* __restrict__ out, int n4) {
  int i = blockIdx.x * 256 + threadIdx.x;
  if (i >= n4) return;
  float4 v = ((const float4*)in)[i];
  ushort4 o;
  o.x = f2bf(v.x); o.y = f2bf(v.y); o.z = f2bf(v.z); o.w = f2bf(v.w);
  ((ushort4*)out)[i] = o;
}

// out[n][k] = bf16(in[k][n]), 1024x1024
__global__ void k_transpose_w(const float* __restrict__ in, u16* __restrict__ out) {
  __shared__ float tile[32][33];
  const int tx = threadIdx.x & 31;
  const int ty = threadIdx.x >> 5;  // 0..7
  const int x0 = blockIdx.x * 32, y0 = blockIdx.y * 32;
  #pragma unroll
  for (int i = 0; i < 32; i += 8)
    tile[ty + i][tx] = in[(size_t)(y0 + ty + i) * 1024 + x0 + tx];
  __syncthreads();
  #pragma unroll
  for (int i = 0; i < 32; i += 8)
    out[(size_t)(x0 + ty + i) * 1024 + y0 + tx] = f2bf(tile[tx][ty + i]);
}

// qscale[n] = Q_SCALE * softplus(pds[n % 128]), n in [0,1024)
__global__ void k_qscale(const float* __restrict__ pds, float* __restrict__ qs, float qscale_c) {
  int n = blockIdx.x * 256 + threadIdx.x;
  float s = pds[n & 127];
  qs[n] = qscale_c * log1pf(expf(s));
}

// relkb[p][n] = bf16( sum_k pos[p][k] * Wrel[k][n] )  (wrt = Wrel^T bf16)
__global__ void k_relk(const float* __restrict__ pos, const u16* __restrict__ wrt,
                       u16* __restrict__ relkb) {
  __shared__ float prow[1024];
  const int tid = threadIdx.x;
  const int p = blockIdx.y;
  ((float4*)prow)[tid] = ((const float4*)(pos + (size_t)p * 1024))[tid];
  __syncthreads();
  int nn = blockIdx.x * 256 + tid;
  const u16* wr = wrt + (size_t)nn * 1024;
  float acc = 0.f;
  for (int kk = 0; kk < 1024; kk += 8) {
    ushort4 u0 = *(const ushort4*)(wr + kk);
    ushort4 u1 = *(const ushort4*)(wr + kk + 4);
    acc += bf2f(u0.x) * prow[kk + 0] + bf2f(u0.y) * prow[kk + 1]
         + bf2f(u0.z) * prow[kk + 2] + bf2f(u0.w) * prow[kk + 3]
         + bf2f(u1.x) * prow[kk + 4] + bf2f(u1.y) * prow[kk + 5]
         + bf2f(u1.z) * prow[kk + 6] + bf2f(u1.w) * prow[kk + 7];
  }
  relkb[(size_t)p * 1024 + nn] = f2bf(acc);
}

// ---------------------------------------------------------------- GEMM (256^2, counted-vmcnt dbuf)
// C[M,N] = A[M,K] @ Bt[N,K]^T ; A,Bt bf16 row-major.
// BM=BN=256, BK=64. 512 threads = 8 waves (2M x 4N), per-wave 128x64 output.
// LDS 128 KiB: 2 dbuf x {A 256x64, B 256x64} bf16, XOR-swizzled on 16B granules
// (granule ^= row&7), applied identically on staging SOURCE (linear global_load_lds
// dest) and on the ds_read side. Raw s_barrier + counted s_waitcnt vmcnt(8) so
// next-tile loads stay in flight across barriers (never drains to 0 in the loop).
// Requires M%256==0, N%256==0, K%64==0, (K/64)>=2 even, gridDim.x%8==0.
// OUTMODE: 0 -> fp32 row-major, 1 -> bf16 row-major, 2 -> bf16 TRANSPOSED (Cout[col*M+row])

#define BAR() __builtin_amdgcn_s_barrier()
#define VMCNT(n) asm volatile("s_waitcnt vmcnt(" #n ")" ::: "memory")

#define STAGE(d, t)                                                                       \
  do {                                                                                    \
    const int koff_ = (t) << 6;                                                           \
    _Pragma("unroll")                                                                     \
    for (int j_ = 0; j_ < 4; ++j_) {                                                      \
      int f_ = tid + j_ * 512;                                                            \
      int r_ = f_ >> 3;                                                                   \
      int cs_ = ((f_ & 7) ^ (r_ & 7)) << 3;                                               \
      __builtin_amdgcn_global_load_lds(                                                   \
          (const AS_GLOBAL u16*)(A + (size_t)(m0 + r_) * K + koff_ + cs_),                \
          (AS_LDS u16*)&lds[d][0][f_ << 3], 16, 0, 0);                                    \
      __builtin_amdgcn_global_load_lds(                                                   \
          (const AS_GLOBAL u16*)(Bt + (size_t)(n0 + r_) * K + koff_ + cs_),               \
          (AS_LDS u16*)&lds[d][1][f_ << 3], 16, 0, 0);                                    \
    }                                                                                     \
  } while (0)

#define COMPUTE(d)                                                                        \
  do {                                                                                    \
    bf16x8 bfr_[4][2];                                                                    \
    _Pragma("unroll")                                                                     \
    for (int ni_ = 0; ni_ < 4; ++ni_) {                                                   \
      int brow_ = wn * 64 + ni_ * 16 + l16;                                               \
      int bb_ = brow_ * 64, bx_ = brow_ & 7;                                              \
      bfr_[ni_][0] = *(const bf16x8*)&lds[d][1][bb_ + ((quad ^ bx_) << 3)];               \
      bfr_[ni_][1] = *(const bf16x8*)&lds[d][1][bb_ + (((4 + quad) ^ bx_) << 3)];         \
    }                                                                                     \
    __builtin_amdgcn_s_setprio(1);                                                        \
    _Pragma("unroll")                                                                     \
    for (int mi_ = 0; mi_ < 8; ++mi_) {                                                   \
      int arow_ = wm * 128 + mi_ * 16 + l16;                                              \
      int ab_ = arow_ * 64, ax_ = arow_ & 7;                                              \
      bf16x8 a0_ = *(const bf16x8*)&lds[d][0][ab_ + ((quad ^ ax_) << 3)];                 \
      bf16x8 a1_ = *(const bf16x8*)&lds[d][0][ab_ + (((4 + quad) ^ ax_) << 3)];           \
      _Pragma("unroll")                                                                   \
      for (int ni_ = 0; ni_ < 4; ++ni_) {                                                 \
        acc[mi_][ni_] =                                                                   \
            __builtin_amdgcn_mfma_f32_16x16x32_bf16(a0_, bfr_[ni_][0], acc[mi_][ni_], 0, 0, 0); \
        acc[mi_][ni_] =                                                                   \
            __builtin_amdgcn_mfma_f32_16x16x32_bf16(a1_, bfr_[ni_][1], acc[mi_][ni_], 0, 0, 0); \
      }                                                                                   \
    }                                                                                     \
    __builtin_amdgcn_s_setprio(0);                                                        \
  } while (0)

template <int OUTMODE>
__global__ __launch_bounds__(512, 2) void k_gemm256(
    const u16* __restrict__ A, const u16* __restrict__ Bt, void* __restrict__ Cout,
    const float* __restrict__ scale_vec, float scale_scalar, int M, int N, int K) {
  __shared__ __align__(16) u16 lds[2][2][16384];  // 128 KiB
  const int tid = threadIdx.x;
  const int wave = tid >> 6, lane = tid & 63;
  const int l16 = lane & 15, quad = lane >> 4;
  const int wm = wave >> 2, wn = wave & 3;  // 2 x 4 wave grid

  // T1: XCD-chunked block swizzle (gridDim.x % 8 == 0), then nt fastest so
  // consecutive same-XCD blocks share the A panel in that XCD's L2.
  const int q8 = (int)gridDim.x >> 3;
  const int wg = ((int)blockIdx.x & 7) * q8 + ((int)blockIdx.x >> 3);
  const int ntn = N >> 8;
  const int m0 = (wg / ntn) << 8;
  const int n0 = (wg % ntn) << 8;

  f32x4 acc[8][4];
  #pragma unroll
  for (int i = 0; i < 8; ++i)
    #pragma unroll
    for (int j = 0; j < 4; ++j) {
      f32x4 z = {0.f, 0.f, 0.f, 0.f};
      acc[i][j] = z;
    }

  STAGE(0, 0);
  STAGE(1, 1);
  VMCNT(8);   // tile 0 landed; tile 1's 8 loads stay in flight
  BAR();

  const int nk = K >> 6;
  for (int i = 0; i + 2 < nk; i += 2) {
    COMPUTE(0);            // tile i
    BAR();                 // all waves done reading buf0
    STAGE(0, i + 2);       // issue tile i+2 into buf0
    VMCNT(8);              // tile i+1 landed (its loads are the oldest)
    BAR();
    COMPUTE(1);            // tile i+1
    BAR();
    STAGE(1, i + 3);
    VMCNT(8);              // tile i+2 landed
    BAR();
  }
  COMPUTE(0);              // tile nk-2
  VMCNT(0);                // drain: tile nk-1 (last in flight)
  BAR();
  COMPUTE(1);              // tile nk-1

  // ---- epilogue
  const int mb = m0 + wm * 128, nb = n0 + wn * 64;
  if (OUTMODE == 2) {
    u16* C = (u16*)Cout;
    #pragma unroll
    for (int ni = 0; ni < 4; ++ni) {
      int col = nb + ni * 16 + l16;
      #pragma unroll
      for (int mi = 0; mi < 8; ++mi) {
        int row = mb + mi * 16 + quad * 4;
        ushort4 o;
        o.x = f2bf(acc[mi][ni][0]);
        o.y = f2bf(acc[mi][ni][1]);
        o.z = f2bf(acc[mi][ni][2]);
        o.w = f2bf(acc[mi][ni][3]);
        *(ushort4*)&C[(size_t)col * M + row] = o;
      }
    }
  } else {
    #pragma unroll
    for (int ni = 0; ni < 4; ++ni) {
      int col = nb + ni * 16 + l16;
      float cs = scale_vec ? scale_vec[col] : scale_scalar;
      #pragma unroll
      for (int mi = 0; mi < 8; ++mi) {
        int row = mb + mi * 16 + quad * 4;
        #pragma unroll
        for (int r = 0; r < 4; ++r) {
          float v = acc[mi][ni][r] * cs;
          if (OUTMODE == 1)
            ((u16*)Cout)[(size_t)(row + r) * N + col] = f2bf(v);
          else
            ((float*)Cout)[(size_t)(row + r) * N + col] = v;
        }
      }
    }
  }
}

// ---------------------------------------------------------------- attention (MFMA, 1 wave per unit)
// unit = (b, n, h); CHUNK=12, PAST=12, CTX=24, P=25, D=128, SOFTCAP=50.
// q,k: [b*2400+s][1024] bf16 rows.  vt: TRANSPOSED [col][38400] bf16 (col = h*128+d), +16 u16 front slack.
// relkb: [32][1024] bf16 (rows 25..31 garbage, never used in output).
// C-layout: col = l16, row = quad*4+reg.  A-layout: A[m=l16][k=quad*8+j].
__global__ __launch_bounds__(256) void k_attn_mfma(
    const u16* __restrict__ q, const u16* __restrict__ k, const u16* __restrict__ vt,
    const u16* __restrict__ relkb, u16* __restrict__ ctx) {
  __shared__ float bdm_s[4][400];     // per-wave [16][25] row-major (flat reindex target)
  __shared__ u16 attnb[4][16 * 32];   // per-wave P matrix, A-layout staging

  const int tid = threadIdx.x;
  const int w = tid >> 6, lane = tid & 63;
  const int l16 = lane & 15, quad = lane >> 4;
  const int id = blockIdx.x * 4 + w;          // 0..25599
  const int b = id / 1600;
  const int rr = id % 1600;
  const int n = rr >> 3, h = rr & 7;
  const int s0 = n * 12;
  const size_t rowbase = (size_t)b * 2400;

  // ---- Q a-frags (m = l16 = q-row, k-chunks c: k = 32c + quad*8 + j)
  bf16x8 qf[4];
  {
    int sq = s0 + l16;
    if (sq > 2399) sq = 2399;  // pad q-rows read real data; outputs never stored
    const u16* qp = q + ((rowbase + sq) * 1024 + (size_t)h * 128 + quad * 8);
    #pragma unroll
    for (int c = 0; c < 4; ++c) qf[c] = *(const bf16x8*)(qp + 32 * c);
  }

  // ---- bd = Q @ rel_k^T  (2 p-tiles), store to LDS [16][25] for flat reindex
  #pragma unroll
  for (int pt = 0; pt < 2; ++pt) {
    int p = pt * 16 + l16;
    const u16* rp = relkb + ((size_t)p * 1024 + (size_t)h * 128 + quad * 8);
    f32x4 acc = {0.f, 0.f, 0.f, 0.f};
    #pragma unroll
    for (int c = 0; c < 4; ++c)
      acc = __builtin_amdgcn_mfma_f32_16x16x32_bf16(qf[c], *(const bf16x8*)(rp + 32 * c), acc, 0, 0, 0);
    if (p < 25) {
      #pragma unroll
      for (int r = 0; r < 4; ++r)
        bdm_s[w][(quad * 4 + r) * 25 + p] = acc[r];
    }
  }
  __threadfence_block();  // LDS write->read ordering within wave

  // ---- ac = Q @ K^T (2 t-tiles) + combine with shifted bd + softcap
  float l0[4], l1[4];
  #pragma unroll
  for (int kt = 0; kt < 2; ++kt) {
    int t = kt * 16 + l16;
    int sk = s0 - 12 + t;
    bool kvalid = ((unsigned)sk < 2400u);
    int ska = kvalid ? sk : 0;
    const u16* kp = k + ((rowbase + ska) * 1024 + (size_t)h * 128 + quad * 8);
    short km = kvalid ? (short)0xFFFF : (short)0;
    bf16x8 kmv = {km, km, km, km, km, km, km, km};
    f32x4 acc = {0.f, 0.f, 0.f, 0.f};
    #pragma unroll
    for (int c = 0; c < 4; ++c) {
      bf16x8 kf = *(const bf16x8*)(kp + 32 * c);
      kf &= kmv;  // zero-padded context rows: ac = 0, bd still enters softmax
      acc = __builtin_amdgcn_mfma_f32_16x16x32_bf16(qf[c], kf, acc, 0, 0, 0);
    }
    #pragma unroll
    for (int r = 0; r < 4; ++r) {
      float bd = bdm_s[w][(quad * 4 + r) * 24 + t];  // rel-shift = flat reindex
      float lg = tanhf((acc[r] + bd) * (1.0f / 50.0f)) * 50.0f;
      if (kt == 1 && l16 >= 8) lg = -INFINITY;  // t >= 24: outside CTX
      if (kt) l1[r] = lg; else l0[r] = lg;
    }
  }

  // ---- softmax over t (row q = quad*4+r lives in a 16-lane group)
  float at0[4], at1[4];
  #pragma unroll
  for (int r = 0; r < 4; ++r) {
    float m = fmaxf(l0[r], l1[r]);
    #pragma unroll
    for (int s = 1; s < 16; s <<= 1) m = fmaxf(m, __shfl_xor(m, s, 64));
    float e0 = __expf(l0[r] - m), e1 = __expf(l1[r] - m);
    float sum = e0 + e1;
    #pragma unroll
    for (int s = 1; s < 16; s <<= 1) sum += __shfl_xor(sum, s, 64);
    float inv = 1.0f / sum;
    at0[r] = e0 * inv;
    at1[r] = e1 * inv;
  }

  // ---- P: C-layout -> A-layout via LDS (bf16)
  #pragma unroll
  for (int r = 0; r < 4; ++r) {
    attnb[w][(quad * 4 + r) * 32 + l16] = f2bf(at0[r]);
    attnb[w][(quad * 4 + r) * 32 + 16 + l16] = f2bf(at1[r]);
  }
  __threadfence_block();
  bf16x8 af = *(const bf16x8*)&attnb[w][l16 * 32 + quad * 8];

  // ---- PV: 8 d-tiles, B-frag = V^T[d][t] contiguous in vt; mask invalid s elements
  int slo = s0 - 12 + quad * 8;
  bf16x8 vmsk;
  #pragma unroll
  for (int j = 0; j < 8; ++j)
    vmsk[j] = ((unsigned)(slo + j) < 2400u) ? (short)0xFFFF : (short)0;

  f32x4 oacc[8];
  #pragma unroll
  for (int dt = 0; dt < 8; ++dt) {
    int col = h * 128 + dt * 16 + l16;
    const u16* vp = vt + ((size_t)col * 38400 + (long)(rowbase + s0 - 12 + quad * 8));
    ushort4 va = *(const ushort4*)vp;
    ushort4 vb = *(const ushort4*)(vp + 4);
    bf16x8 vf = {(short)va.x, (short)va.y, (short)va.z, (short)va.w,
                 (short)vb.x, (short)vb.y, (short)vb.z, (short)vb.w};
    vf &= vmsk;
    f32x4 z = {0.f, 0.f, 0.f, 0.f};
    oacc[dt] = __builtin_amdgcn_mfma_f32_16x16x32_bf16(af, vf, z, 0, 0, 0);
  }

  // ---- store O (rows q = quad*4+r, only q<12 valid -> quads 0..2)
  if (quad < 3) {
    #pragma unroll
    for (int dt = 0; dt < 8; ++dt) {
      int col = h * 128 + dt * 16 + l16;
      #pragma unroll
      for (int r = 0; r < 4; ++r) {
        int qi = quad * 4 + r;
        ctx[(rowbase + s0 + qi) * 1024 + col] = f2bf(oacc[dt][r]);
      }
    }
  }
}

// ---------------------------------------------------------------- launch

extern "C" void kernel_launch(void* const* d_in, const int* in_sizes, int n_in,
                              void* d_out, int out_size, void* d_ws, size_t ws_size,
                              hipStream_t stream) {
  const float* x       = (const float*)d_in[0];  // [16,2400,1024]
  const float* pos_emb = (const float*)d_in[1];  // [25,1024]
  const float* Wq      = (const float*)d_in[2];
  const float* Wk      = (const float*)d_in[3];
  const float* Wv      = (const float*)d_in[4];
  const float* Wpost   = (const float*)d_in[5];
  const float* Wrel    = (const float*)d_in[6];
  const float* pds     = (const float*)d_in[7];  // [128]
  float* out = (float*)d_out;

  const int M = 38400, HS = 1024;           // M = B*S = 16*2400
  const size_t XE = (size_t)M * HS;

  // workspace layout (u16 units)
  u16* xbf = (u16*)d_ws;                 // XE; reused as ctx after QKV GEMMs consume it
  u16* qbf = xbf + XE;                   // XE
  u16* kbf = qbf + XE;                   // XE
  u16* vt_alloc = kbf + XE;              // XE + 64 (slack for boundary-masked loads)
  u16* vt = vt_alloc + 16;
  u16* wqt = vt_alloc + XE + 64;
  u16* wkt = wqt + (size_t)HS * HS;
  u16* wvt = wkt + (size_t)HS * HS;
  u16* wrt = wvt + (size_t)HS * HS;
  u16* wpt = wrt + (size_t)HS * HS;
  u16* relkb = wpt + (size_t)HS * HS;    // 32*1024 (rows 25..31 unwritten, harmless)
  float* qsc = (float*)(relkb + 32 * 1024);

  const double LN2 = 0.6931471805599453;
  const float QS = (float)((1.0 / sqrt(128.0)) / LN2);
  const float KS = (float)(log(1.0 + exp(1.0)) / LN2);

  // 1) x -> bf16
  k_f32_to_bf16<<<(int)(XE / 4 / 256), 256, 0, stream>>>(x, xbf, (int)(XE / 4));
  // 2) transpose weights -> bf16 [n][k]
  dim3 tg(32, 32);
  k_transpose_w<<<tg, 256, 0, stream>>>(Wq, wqt);
  k_transpose_w<<<tg, 256, 0, stream>>>(Wk, wkt);
  k_transpose_w<<<tg, 256, 0, stream>>>(Wv, wvt);
  k_transpose_w<<<tg, 256, 0, stream>>>(Wrel, wrt);
  k_transpose_w<<<tg, 256, 0, stream>>>(Wpost, wpt);
  // 3) per-column q scale
  k_qscale<<<4, 256, 0, stream>>>(pds, qsc, QS);
  // 4) rel_k = pos_emb @ Wrel -> bf16
  k_relk<<<dim3(4, 25), 256, 0, stream>>>(pos_emb, wrt, relkb);
  // 5) QKV projections (256^2 tiles: grid = (38400/256)*(1024/256) = 600, %8==0)
  const int NWG = (M / 256) * (HS / 256);  // 600
  k_gemm256<1><<<NWG, 512, 0, stream>>>(xbf, wqt, qbf, qsc, 1.0f, M, HS, HS);
  k_gemm256<1><<<NWG, 512, 0, stream>>>(xbf, wkt, kbf, nullptr, KS, M, HS, HS);
  k_gemm256<2><<<NWG, 512, 0, stream>>>(xbf, wvt, vt, nullptr, 1.0f, M, HS, HS);  // V transposed
  // 6) attention -> ctx (reuses xbf region; stream-ordered after QKV reads)
  k_attn_mfma<<<25600 / 4, 256, 0, stream>>>(qbf, kbf, vt, relkb, xbf);
  // 7) out = ctx @ Wpost (fp32 out)
  k_gemm256<0><<<NWG, 512, 0, stream>>>(xbf, wpt, out, nullptr, 1.0f, M, HS, HS);
}

// Round 3
// 862.259 us; speedup vs baseline: 1.1022x; 1.0206x over previous
//
#include <hip/hip_runtime.h>
#include <hip/hip_bf16.h>
#include <cmath>

#define AS_GLOBAL __attribute__((address_space(1)))
#define AS_LDS    __attribute__((address_space(3)))

typedef __attribute__((ext_vector_type(8))) short bf16x8;
typedef __attribute__((ext_vector_type(4))) float f32x4;
typedef unsigned short u16;

__device__ __forceinline__ u16 f2bf(float f) {
  union { __hip_bfloat16 h; u16 u; } cv;
  cv.h = __float2bfloat16(f);
  return cv.u;
}
__device__ __forceinline__ float bf2f(u16 u) {
  union { unsigned u32; float f; } v;
  v.u32 = ((unsigned)u) << 16;
  return v.f;
}

// ---------------------------------------------------------------- prep kernels

__global__ void k_f32_to_bf16(const float* __restrict__ in, u16* __restrict__ out, int n4) {
  int i = blockIdx.x * 256 + threadIdx.x;
  if (i >= n4) return;
  float4 v = ((const float4*)in)[i];
  ushort4 o;
  o.x = f2bf(v.x); o.y = f2bf(v.y); o.z = f2bf(v.z); o.w = f2bf(v.w);
  ((ushort4*)out)[i] = o;
}

// out[n][k] = bf16(in[k][n]), 1024x1024
__global__ void k_transpose_w(const float* __restrict__ in, u16* __restrict__ out) {
  __shared__ float tile[32][33];
  const int tx = threadIdx.x & 31;
  const int ty = threadIdx.x >> 5;  // 0..7
  const int x0 = blockIdx.x * 32, y0 = blockIdx.y * 32;
  #pragma unroll
  for (int i = 0; i < 32; i += 8)
    tile[ty + i][tx] = in[(size_t)(y0 + ty + i) * 1024 + x0 + tx];
  __syncthreads();
  #pragma unroll
  for (int i = 0; i < 32; i += 8)
    out[(size_t)(x0 + ty + i) * 1024 + y0 + tx] = f2bf(tile[tx][ty + i]);
}

// qscale[n] = Q_SCALE * softplus(pds[n % 128]), n in [0,1024)
__global__ void k_qscale(const float* __restrict__ pds, float* __restrict__ qs, float qscale_c) {
  int n = blockIdx.x * 256 + threadIdx.x;
  float s = pds[n & 127];
  qs[n] = qscale_c * log1pf(expf(s));
}

// relkb[p][n] = bf16( sum_k pos[p][k] * Wrel[k][n] )  (wrt = Wrel^T bf16)
__global__ void k_relk(const float* __restrict__ pos, const u16* __restrict__ wrt,
                       u16* __restrict__ relkb) {
  __shared__ float prow[1024];
  const int tid = threadIdx.x;
  const int p = blockIdx.y;
  ((float4*)prow)[tid] = ((const float4*)(pos + (size_t)p * 1024))[tid];
  __syncthreads();
  int nn = blockIdx.x * 256 + tid;
  const u16* wr = wrt + (size_t)nn * 1024;
  float acc = 0.f;
  for (int kk = 0; kk < 1024; kk += 8) {
    ushort4 u0 = *(const ushort4*)(wr + kk);
    ushort4 u1 = *(const ushort4*)(wr + kk + 4);
    acc += bf2f(u0.x) * prow[kk + 0] + bf2f(u0.y) * prow[kk + 1]
         + bf2f(u0.z) * prow[kk + 2] + bf2f(u0.w) * prow[kk + 3]
         + bf2f(u1.x) * prow[kk + 4] + bf2f(u1.y) * prow[kk + 5]
         + bf2f(u1.z) * prow[kk + 6] + bf2f(u1.w) * prow[kk + 7];
  }
  relkb[(size_t)p * 1024 + nn] = f2bf(acc);
}

// ---------------------------------------------------------------- GEMM (256^2, 8-phase T3+T4 schedule)
// C[M,N] = A[M,K] @ Bt[N,K]^T ; A,Bt bf16 row-major.
// BM=BN=256, BK=64. 512 threads = 8 waves (2M x 4N), per-wave 128x64 output.
// LDS 128 KiB: 2 dbuf x {A 256x64, B 256x64} bf16; granule swizzle g^=(row&7) on both
// stage-source and ds_read (rule 21). 8 phases per 2 K-tiles; each phase = {ds-read one
// C-quadrant's frags || stage one 16KB chunk (2 gload_lds) -> s_barrier -> 16 MFMA
// (setprio) -> counted vmcnt -> s_barrier}. Chunk split matches quadrant read-sets:
//   A-chunk h = rows with ((r>>6)&1)==h, read only in phases with q_m==h
//   B-chunk h = rows with ((r>>5)&1)==h, read only in phases with q_n==h
// Phase order per tile: (qm,qn) = (0,0),(1,0),(1,1),(0,1) -> frag reuse, 32 ds_reads/tile.
// Steady-state waits vmcnt(8)/(6) at phases 1,3,5,7 (verified free/stage/wait chain);
// vmcnt reaches 0 only in the peeled final iteration. sched_barrier(0) after each wait
// pins gload_lds issue order against compiler migration (defensive).
// Requires M%256==0, N%256==0, K%64==0, (K/64) even >=4, gridDim.x%8==0.
// OUTMODE: 0 -> fp32 row-major, 1 -> bf16 row-major, 2 -> bf16 TRANSPOSED (Cout[col*M+row])

#define VMCNT(n) do { asm volatile("s_waitcnt vmcnt(" #n ")" ::: "memory"); \
                      __builtin_amdgcn_sched_barrier(0); } while (0)
#define BARF() do { asm volatile("" ::: "memory"); __builtin_amdgcn_s_barrier(); asm volatile("" ::: "memory"); } while (0)
#define GLD(SRC, DST) __builtin_amdgcn_global_load_lds((const AS_GLOBAL u16*)(SRC), (AS_LDS u16*)(DST), 16, 0, 0)
#define LDSA(d) ((AS_LDS char*)&lds[d][0][0])
#define LDSB(d) ((AS_LDS char*)&lds[d][1][0])

#define STAGE_A(d, h, t) do {                                                   \
  GLD(sA0 + (((size_t)(h)) << 6) * K + ((t) << 6), LDSA(d) + dA0 + ((h) << 13)); \
  GLD(sA1 + (((size_t)(h)) << 6) * K + ((t) << 6), LDSA(d) + dA1 + ((h) << 13)); \
} while (0)
#define STAGE_B(d, h, t) do {                                                   \
  GLD(sB0 + (((size_t)(h)) << 5) * K + ((t) << 6), LDSB(d) + dB0 + ((h) << 12)); \
  GLD(sB1 + (((size_t)(h)) << 5) * K + ((t) << 6), LDSB(d) + dB1 + ((h) << 12)); \
} while (0)

#define LOAD_A(d, qm) do {                                                       \
  _Pragma("unroll") for (int mi_ = 0; mi_ < 4; ++mi_) {                          \
    af[mi_][0] = *(const bf16x8*)&lds[d][0][abase + (((qm)*64 + mi_*16) << 6) + gk0]; \
    af[mi_][1] = *(const bf16x8*)&lds[d][0][abase + (((qm)*64 + mi_*16) << 6) + gk1]; \
  } } while (0)
#define LOAD_B(d, qn) do {                                                       \
  _Pragma("unroll") for (int ni_ = 0; ni_ < 2; ++ni_) {                          \
    bfb[ni_][0] = *(const bf16x8*)&lds[d][1][bbase + (((qn)*32 + ni_*16) << 6) + gk0]; \
    bfb[ni_][1] = *(const bf16x8*)&lds[d][1][bbase + (((qn)*32 + ni_*16) << 6) + gk1]; \
  } } while (0)
#define MFMA16(qm, qn) do {                                                      \
  __builtin_amdgcn_s_setprio(1);                                                 \
  _Pragma("unroll") for (int mi_ = 0; mi_ < 4; ++mi_)                            \
  _Pragma("unroll") for (int ni_ = 0; ni_ < 2; ++ni_) {                          \
    acc[(qm)*4+mi_][(qn)*2+ni_] = __builtin_amdgcn_mfma_f32_16x16x32_bf16(       \
        af[mi_][0], bfb[ni_][0], acc[(qm)*4+mi_][(qn)*2+ni_], 0, 0, 0);          \
    acc[(qm)*4+mi_][(qn)*2+ni_] = __builtin_amdgcn_mfma_f32_16x16x32_bf16(       \
        af[mi_][1], bfb[ni_][1], acc[(qm)*4+mi_][(qn)*2+ni_], 0, 0, 0);          \
  }                                                                              \
  __builtin_amdgcn_s_setprio(0); } while (0)

template <int OUTMODE>
__global__ __launch_bounds__(512, 2) void k_gemm256(
    const u16* __restrict__ A, const u16* __restrict__ Bt, void* __restrict__ Cout,
    const float* __restrict__ scale_vec, float scale_scalar, int M, int N, int K) {
  __shared__ __align__(16) u16 lds[2][2][16384];  // 128 KiB
  const int tid = threadIdx.x;
  const int wave = tid >> 6, lane = tid & 63;
  const int l16 = lane & 15, quad = lane >> 4;
  const int wm = wave >> 2, wn = wave & 3;  // 2 x 4 wave grid

  // T1: XCD-chunked block swizzle (gridDim.x % 8 == 0)
  const int q8 = (int)gridDim.x >> 3;
  const int wg = ((int)blockIdx.x & 7) * q8 + ((int)blockIdx.x >> 3);
  const int ntn = N >> 8;
  const int m0 = (wg / ntn) << 8;
  const int n0 = (wg % ntn) << 8;

  // ---- ds_read constants (frag layout identical to verified round-1 kernel)
  const int sx = l16 & 7;
  const int gk0 = (quad ^ sx) << 3;        // u16 offset, kk=0 granule
  const int gk1 = ((4 + quad) ^ sx) << 3;  // kk=1 granule
  const int abase = (wm * 128 + l16) << 6;
  const int bbase = (wn * 64 + l16) << 6;

  // ---- staging constants (per-thread, hoisted)
  const int rl0 = tid >> 3, g0 = tid & 7;
  const int rl1 = rl0 + 64;                         // (rl1&7)==(rl0&7)
  const int swz0 = (g0 ^ (rl0 & 7)) << 3;           // u16 source-col swizzle
  const int rbA0 = ((rl0 >> 6) << 7) + (rl0 & 63);  // A-chunk h=0 rows {0..63, 128..191}
  const int rbA1 = ((rl1 >> 6) << 7) + (rl1 & 63);
  const int rbB0 = ((rl0 >> 5) << 6) + (rl0 & 31);  // B-chunk h=0 rows {0..31,64..95,...}
  const int rbB1 = ((rl1 >> 5) << 6) + (rl1 & 31);
  const u16* sA0 = A + (size_t)(m0 + rbA0) * K + swz0;
  const u16* sA1 = A + (size_t)(m0 + rbA1) * K + swz0;
  const u16* sB0 = Bt + (size_t)(n0 + rbB0) * K + swz0;
  const u16* sB1 = Bt + (size_t)(n0 + rbB1) * K + swz0;
  const int dA0 = (rbA0 << 7) + (g0 << 4);  // byte offsets (linear dest: base+lane*16)
  const int dA1 = (rbA1 << 7) + (g0 << 4);
  const int dB0 = (rbB0 << 7) + (g0 << 4);
  const int dB1 = (rbB1 << 7) + (g0 << 4);

  f32x4 acc[8][4];
  #pragma unroll
  for (int i = 0; i < 8; ++i)
    #pragma unroll
    for (int j = 0; j < 4; ++j) {
      f32x4 z = {0.f, 0.f, 0.f, 0.f};
      acc[i][j] = z;
    }

  bf16x8 af[4][2], bfb[2][2];

  // ---- prologue: issue order == steady-state in-flight pattern [prevP2..prevP7]
  STAGE_B(0, 0, 0);  // T0.B0
  STAGE_A(0, 1, 0);  // T0.A1
  STAGE_A(0, 0, 0);  // T0.A0
  STAGE_B(0, 1, 0);  // T0.B1
  STAGE_B(1, 0, 1);  // T1.B0'
  STAGE_A(1, 1, 1);  // T1.A1'
  VMCNT(6);          // T0.{B0,A1,A0} landed
  BARF();

  const int nk = K >> 6;
  for (int i = 0; i < (nk >> 1) - 1; ++i) {
    const int t1 = 2 * i + 1, t2 = 2 * i + 2, t3 = 2 * i + 3;
    // P0 (buf0, qm=0 qn=0)
    LOAD_A(0, 0); LOAD_B(0, 0);
    STAGE_A(1, 0, t1);                        // buf1.A0 <- T1 (freed after prev P7)
    BARF(); MFMA16(0, 0); BARF();
    // P1 (qm=1 qn=0)
    LOAD_A(0, 1);
    STAGE_B(1, 1, t1);                        // buf1.B1 <- T1
    BARF(); MFMA16(1, 0); VMCNT(8); BARF();   // -> T0.B1 landed (P2 reads)
    // P2 (qm=1 qn=1)
    LOAD_B(0, 1);
    STAGE_B(0, 0, t2);                        // buf0.B0 <- T2 (freed after P1)
    BARF(); MFMA16(1, 1); BARF();
    // P3 (qm=0 qn=1)
    LOAD_A(0, 0);
    STAGE_A(0, 1, t2);                        // buf0.A1 <- T2 (freed after P2)
    BARF(); MFMA16(0, 1); VMCNT(6); BARF();   // -> T1.{A0,B0} landed (P4 reads)
    // P4 (buf1, qm=0 qn=0)
    LOAD_A(1, 0); LOAD_B(1, 0);
    STAGE_A(0, 0, t2);                        // buf0.A0 <- T2 (freed after P3)
    BARF(); MFMA16(0, 0); BARF();
    // P5 (qm=1 qn=0)
    LOAD_A(1, 1);
    STAGE_B(0, 1, t2);                        // buf0.B1 <- T2 (freed after P3)
    BARF(); MFMA16(1, 0); VMCNT(8); BARF();   // -> T1.B1 landed (P6 reads)
    // P6 (qm=1 qn=1)
    LOAD_B(1, 1);
    STAGE_B(1, 0, t3);                        // buf1.B0 <- T3 (freed after P5)
    BARF(); MFMA16(1, 1); BARF();
    // P7 (qm=0 qn=1)
    LOAD_A(1, 0);
    STAGE_A(1, 1, t3);                        // buf1.A1 <- T3 (freed after P6)
    BARF(); MFMA16(0, 1); VMCNT(6); BARF();   // -> next-T0.{B0,A1,A0} landed
  }

  // ---- peeled final iteration: tiles nk-2, nk-1 (no T2/T3 staging)
  {
    const int t1 = nk - 1;
    // P0
    LOAD_A(0, 0); LOAD_B(0, 0);
    STAGE_A(1, 0, t1);                        // T1.A0'
    BARF(); MFMA16(0, 0); BARF();
    // P1
    LOAD_A(0, 1);
    STAGE_B(1, 1, t1);                        // T1.B1'
    BARF(); MFMA16(1, 0); VMCNT(8); BARF();   // T0.B1 landed
    // P2
    LOAD_B(0, 1);
    BARF(); MFMA16(1, 1); BARF();
    // P3
    LOAD_A(0, 0);
    BARF(); MFMA16(0, 1); VMCNT(2); BARF();   // T1.{B0',A1',A0'} landed
    // P4
    LOAD_A(1, 0); LOAD_B(1, 0);
    BARF(); MFMA16(0, 0); BARF();
    // P5
    LOAD_A(1, 1);
    BARF(); MFMA16(1, 0); VMCNT(0); BARF();   // T1.B1' landed
    // P6
    LOAD_B(1, 1);
    BARF(); MFMA16(1, 1); BARF();
    // P7
    LOAD_A(1, 0);
    BARF(); MFMA16(0, 1);
  }

  // ---- epilogue
  const int mb = m0 + wm * 128, nb = n0 + wn * 64;
  if (OUTMODE == 2) {
    u16* C = (u16*)Cout;
    #pragma unroll
    for (int ni = 0; ni < 4; ++ni) {
      int col = nb + ni * 16 + l16;
      #pragma unroll
      for (int mi = 0; mi < 8; ++mi) {
        int row = mb + mi * 16 + quad * 4;
        ushort4 o;
        o.x = f2bf(acc[mi][ni][0]);
        o.y = f2bf(acc[mi][ni][1]);
        o.z = f2bf(acc[mi][ni][2]);
        o.w = f2bf(acc[mi][ni][3]);
        *(ushort4*)&C[(size_t)col * M + row] = o;
      }
    }
  } else {
    #pragma unroll
    for (int ni = 0; ni < 4; ++ni) {
      int col = nb + ni * 16 + l16;
      float cs = scale_vec ? scale_vec[col] : scale_scalar;
      #pragma unroll
      for (int mi = 0; mi < 8; ++mi) {
        int row = mb + mi * 16 + quad * 4;
        #pragma unroll
        for (int r = 0; r < 4; ++r) {
          float v = acc[mi][ni][r] * cs;
          if (OUTMODE == 1)
            ((u16*)Cout)[(size_t)(row + r) * N + col] = f2bf(v);
          else
            ((float*)Cout)[(size_t)(row + r) * N + col] = v;
        }
      }
    }
  }
}

#undef STAGE_A
#undef STAGE_B
#undef LOAD_A
#undef LOAD_B
#undef MFMA16

// ---------------------------------------------------------------- attention (MFMA, 1 wave per unit)
// unit = (b, n, h); CHUNK=12, PAST=12, CTX=24, P=25, D=128, SOFTCAP=50.
// q,k: [b*2400+s][1024] bf16 rows.  vt: TRANSPOSED [col][38400] bf16 (col = h*128+d), +16 u16 front slack.
// relkb: [32][1024] bf16 (rows 25..31 garbage, never used in output).
// C-layout: col = l16, row = quad*4+reg.  A-layout: A[m=l16][k=quad*8+j].
__global__ __launch_bounds__(256) void k_attn_mfma(
    const u16* __restrict__ q, const u16* __restrict__ k, const u16* __restrict__ vt,
    const u16* __restrict__ relkb, u16* __restrict__ ctx) {
  __shared__ float bdm_s[4][400];     // per-wave [16][25] row-major (flat reindex target)
  __shared__ u16 attnb[4][16 * 32];   // per-wave P matrix, A-layout staging

  const int tid = threadIdx.x;
  const int w = tid >> 6, lane = tid & 63;
  const int l16 = lane & 15, quad = lane >> 4;
  const int id = blockIdx.x * 4 + w;          // 0..25599
  const int b = id / 1600;
  const int rr = id % 1600;
  const int n = rr >> 3, h = rr & 7;
  const int s0 = n * 12;
  const size_t rowbase = (size_t)b * 2400;

  // ---- Q a-frags (m = l16 = q-row, k-chunks c: k = 32c + quad*8 + j)
  bf16x8 qf[4];
  {
    int sq = s0 + l16;
    if (sq > 2399) sq = 2399;  // pad q-rows read real data; outputs never stored
    const u16* qp = q + ((rowbase + sq) * 1024 + (size_t)h * 128 + quad * 8);
    #pragma unroll
    for (int c = 0; c < 4; ++c) qf[c] = *(const bf16x8*)(qp + 32 * c);
  }

  // ---- bd = Q @ rel_k^T  (2 p-tiles), store to LDS [16][25] for flat reindex
  #pragma unroll
  for (int pt = 0; pt < 2; ++pt) {
    int p = pt * 16 + l16;
    const u16* rp = relkb + ((size_t)p * 1024 + (size_t)h * 128 + quad * 8);
    f32x4 acc = {0.f, 0.f, 0.f, 0.f};
    #pragma unroll
    for (int c = 0; c < 4; ++c)
      acc = __builtin_amdgcn_mfma_f32_16x16x32_bf16(qf[c], *(const bf16x8*)(rp + 32 * c), acc, 0, 0, 0);
    if (p < 25) {
      #pragma unroll
      for (int r = 0; r < 4; ++r)
        bdm_s[w][(quad * 4 + r) * 25 + p] = acc[r];
    }
  }
  __threadfence_block();  // LDS write->read ordering within wave

  // ---- ac = Q @ K^T (2 t-tiles) + combine with shifted bd + softcap
  float l0[4], l1[4];
  #pragma unroll
  for (int kt = 0; kt < 2; ++kt) {
    int t = kt * 16 + l16;
    int sk = s0 - 12 + t;
    bool kvalid = ((unsigned)sk < 2400u);
    int ska = kvalid ? sk : 0;
    const u16* kp = k + ((rowbase + ska) * 1024 + (size_t)h * 128 + quad * 8);
    short km = kvalid ? (short)0xFFFF : (short)0;
    bf16x8 kmv = {km, km, km, km, km, km, km, km};
    f32x4 acc = {0.f, 0.f, 0.f, 0.f};
    #pragma unroll
    for (int c = 0; c < 4; ++c) {
      bf16x8 kf = *(const bf16x8*)(kp + 32 * c);
      kf &= kmv;  // zero-padded context rows: ac = 0, bd still enters softmax
      acc = __builtin_amdgcn_mfma_f32_16x16x32_bf16(qf[c], kf, acc, 0, 0, 0);
    }
    #pragma unroll
    for (int r = 0; r < 4; ++r) {
      float bd = bdm_s[w][(quad * 4 + r) * 24 + t];  // rel-shift = flat reindex
      float lg = tanhf((acc[r] + bd) * (1.0f / 50.0f)) * 50.0f;
      if (kt == 1 && l16 >= 8) lg = -INFINITY;  // t >= 24: outside CTX
      if (kt) l1[r] = lg; else l0[r] = lg;
    }
  }

  // ---- softmax over t (row q = quad*4+r lives in a 16-lane group)
  float at0[4], at1[4];
  #pragma unroll
  for (int r = 0; r < 4; ++r) {
    float m = fmaxf(l0[r], l1[r]);
    #pragma unroll
    for (int s = 1; s < 16; s <<= 1) m = fmaxf(m, __shfl_xor(m, s, 64));
    float e0 = __expf(l0[r] - m), e1 = __expf(l1[r] - m);
    float sum = e0 + e1;
    #pragma unroll
    for (int s = 1; s < 16; s <<= 1) sum += __shfl_xor(sum, s, 64);
    float inv = 1.0f / sum;
    at0[r] = e0 * inv;
    at1[r] = e1 * inv;
  }

  // ---- P: C-layout -> A-layout via LDS (bf16)
  #pragma unroll
  for (int r = 0; r < 4; ++r) {
    attnb[w][(quad * 4 + r) * 32 + l16] = f2bf(at0[r]);
    attnb[w][(quad * 4 + r) * 32 + 16 + l16] = f2bf(at1[r]);
  }
  __threadfence_block();
  bf16x8 af = *(const bf16x8*)&attnb[w][l16 * 32 + quad * 8];

  // ---- PV: 8 d-tiles, B-frag = V^T[d][t] contiguous in vt; mask invalid s elements
  int slo = s0 - 12 + quad * 8;
  bf16x8 vmsk;
  #pragma unroll
  for (int j = 0; j < 8; ++j)
    vmsk[j] = ((unsigned)(slo + j) < 2400u) ? (short)0xFFFF : (short)0;

  f32x4 oacc[8];
  #pragma unroll
  for (int dt = 0; dt < 8; ++dt) {
    int col = h * 128 + dt * 16 + l16;
    const u16* vp = vt + ((size_t)col * 38400 + (long)(rowbase + s0 - 12 + quad * 8));
    ushort4 va = *(const ushort4*)vp;
    ushort4 vb = *(const ushort4*)(vp + 4);
    bf16x8 vf = {(short)va.x, (short)va.y, (short)va.z, (short)va.w,
                 (short)vb.x, (short)vb.y, (short)vb.z, (short)vb.w};
    vf &= vmsk;
    f32x4 z = {0.f, 0.f, 0.f, 0.f};
    oacc[dt] = __builtin_amdgcn_mfma_f32_16x16x32_bf16(af, vf, z, 0, 0, 0);
  }

  // ---- store O (rows q = quad*4+r, only q<12 valid -> quads 0..2)
  if (quad < 3) {
    #pragma unroll
    for (int dt = 0; dt < 8; ++dt) {
      int col = h * 128 + dt * 16 + l16;
      #pragma unroll
      for (int r = 0; r < 4; ++r) {
        int qi = quad * 4 + r;
        ctx[(rowbase + s0 + qi) * 1024 + col] = f2bf(oacc[dt][r]);
      }
    }
  }
}

// ---------------------------------------------------------------- launch

extern "C" void kernel_launch(void* const* d_in, const int* in_sizes, int n_in,
                              void* d_out, int out_size, void* d_ws, size_t ws_size,
                              hipStream_t stream) {
  const float* x       = (const float*)d_in[0];  // [16,2400,1024]
  const float* pos_emb = (const float*)d_in[1];  // [25,1024]
  const float* Wq      = (const float*)d_in[2];
  const float* Wk      = (const float*)d_in[3];
  const float* Wv      = (const float*)d_in[4];
  const float* Wpost   = (const float*)d_in[5];
  const float* Wrel    = (const float*)d_in[6];
  const float* pds     = (const float*)d_in[7];  // [128]
  float* out = (float*)d_out;

  const int M = 38400, HS = 1024;           // M = B*S = 16*2400
  const size_t XE = (size_t)M * HS;

  // workspace layout (u16 units)
  u16* xbf = (u16*)d_ws;                 // XE; reused as ctx after QKV GEMMs consume it
  u16* qbf = xbf + XE;                   // XE
  u16* kbf = qbf + XE;                   // XE
  u16* vt_alloc = kbf + XE;              // XE + 64 (slack for boundary-masked loads)
  u16* vt = vt_alloc + 16;
  u16* wqt = vt_alloc + XE + 64;
  u16* wkt = wqt + (size_t)HS * HS;
  u16* wvt = wkt + (size_t)HS * HS;
  u16* wrt = wvt + (size_t)HS * HS;
  u16* wpt = wrt + (size_t)HS * HS;
  u16* relkb = wpt + (size_t)HS * HS;    // 32*1024 (rows 25..31 unwritten, harmless)
  float* qsc = (float*)(relkb + 32 * 1024);

  const double LN2 = 0.6931471805599453;
  const float QS = (float)((1.0 / sqrt(128.0)) / LN2);
  const float KS = (float)(log(1.0 + exp(1.0)) / LN2);

  // 1) x -> bf16
  k_f32_to_bf16<<<(int)(XE / 4 / 256), 256, 0, stream>>>(x, xbf, (int)(XE / 4));
  // 2) transpose weights -> bf16 [n][k]
  dim3 tg(32, 32);
  k_transpose_w<<<tg, 256, 0, stream>>>(Wq, wqt);
  k_transpose_w<<<tg, 256, 0, stream>>>(Wk, wkt);
  k_transpose_w<<<tg, 256, 0, stream>>>(Wv, wvt);
  k_transpose_w<<<tg, 256, 0, stream>>>(Wrel, wrt);
  k_transpose_w<<<tg, 256, 0, stream>>>(Wpost, wpt);
  // 3) per-column q scale
  k_qscale<<<4, 256, 0, stream>>>(pds, qsc, QS);
  // 4) rel_k = pos_emb @ Wrel -> bf16
  k_relk<<<dim3(4, 25), 256, 0, stream>>>(pos_emb, wrt, relkb);
  // 5) QKV projections (256^2 tiles: grid = (38400/256)*(1024/256) = 600, %8==0)
  const int NWG = (M / 256) * (HS / 256);  // 600
  k_gemm256<1><<<NWG, 512, 0, stream>>>(xbf, wqt, qbf, qsc, 1.0f, M, HS, HS);
  k_gemm256<1><<<NWG, 512, 0, stream>>>(xbf, wkt, kbf, nullptr, KS, M, HS, HS);
  k_gemm256<2><<<NWG, 512, 0, stream>>>(xbf, wvt, vt, nullptr, 1.0f, M, HS, HS);  // V transposed
  // 6) attention -> ctx (reuses xbf region; stream-ordered after QKV reads)
  k_attn_mfma<<<25600 / 4, 256, 0, stream>>>(qbf, kbf, vt, relkb, xbf);
  // 7) out = ctx @ Wpost (fp32 out)
  k_gemm256<0><<<NWG, 512, 0, stream>>>(xbf, wpt, out, nullptr, 1.0f, M, HS, HS);
}

// Round 5
// 798.341 us; speedup vs baseline: 1.1904x; 1.0801x over previous
//
#include <hip/hip_runtime.h>
#include <hip/hip_bf16.h>
#include <cmath>

#define AS_GLOBAL __attribute__((address_space(1)))
#define AS_LDS    __attribute__((address_space(3)))

typedef __attribute__((ext_vector_type(8))) short bf16x8;
typedef __attribute__((ext_vector_type(4))) float f32x4;
typedef unsigned short u16;

__device__ __forceinline__ u16 f2bf(float f) {
  union { __hip_bfloat16 h; u16 u; } cv;
  cv.h = __float2bfloat16(f);
  return cv.u;
}
__device__ __forceinline__ float bf2f(u16 u) {
  union { unsigned u32; float f; } v;
  v.u32 = ((unsigned)u) << 16;
  return v.f;
}

// ---------------------------------------------------------------- prep kernels

__global__ void k_f32_to_bf16(const float* __restrict__ in, u16* __restrict__ out, int n4) {
  int i = blockIdx.x * 256 + threadIdx.x;
  if (i >= n4) return;
  float4 v = ((const float4*)in)[i];
  ushort4 o;
  o.x = f2bf(v.x); o.y = f2bf(v.y); o.z = f2bf(v.z); o.w = f2bf(v.w);
  ((ushort4*)out)[i] = o;
}

// out[n][k] = bf16(in[k][n]), 1024x1024
__global__ void k_transpose_w(const float* __restrict__ in, u16* __restrict__ out) {
  __shared__ float tile[32][33];
  const int tx = threadIdx.x & 31;
  const int ty = threadIdx.x >> 5;  // 0..7
  const int x0 = blockIdx.x * 32, y0 = blockIdx.y * 32;
  #pragma unroll
  for (int i = 0; i < 32; i += 8)
    tile[ty + i][tx] = in[(size_t)(y0 + ty + i) * 1024 + x0 + tx];
  __syncthreads();
  #pragma unroll
  for (int i = 0; i < 32; i += 8)
    out[(size_t)(x0 + ty + i) * 1024 + y0 + tx] = f2bf(tile[tx][ty + i]);
}

// qscale[n] = Q_SCALE * softplus(pds[n % 128]), n in [0,1024)
__global__ void k_qscale(const float* __restrict__ pds, float* __restrict__ qs, float qscale_c) {
  int n = blockIdx.x * 256 + threadIdx.x;
  float s = pds[n & 127];
  qs[n] = qscale_c * log1pf(expf(s));
}

// relkb[p][n] = bf16( sum_k pos[p][k] * Wrel[k][n] )  (wrt = Wrel^T bf16)
__global__ void k_relk(const float* __restrict__ pos, const u16* __restrict__ wrt,
                       u16* __restrict__ relkb) {
  __shared__ float prow[1024];
  const int tid = threadIdx.x;
  const int p = blockIdx.y;
  ((float4*)prow)[tid] = ((const float4*)(pos + (size_t)p * 1024))[tid];
  __syncthreads();
  int nn = blockIdx.x * 256 + tid;
  const u16* wr = wrt + (size_t)nn * 1024;
  float acc = 0.f;
  for (int kk = 0; kk < 1024; kk += 8) {
    ushort4 u0 = *(const ushort4*)(wr + kk);
    ushort4 u1 = *(const ushort4*)(wr + kk + 4);
    acc += bf2f(u0.x) * prow[kk + 0] + bf2f(u0.y) * prow[kk + 1]
         + bf2f(u0.z) * prow[kk + 2] + bf2f(u0.w) * prow[kk + 3]
         + bf2f(u1.x) * prow[kk + 4] + bf2f(u1.y) * prow[kk + 5]
         + bf2f(u1.z) * prow[kk + 6] + bf2f(u1.w) * prow[kk + 7];
  }
  relkb[(size_t)p * 1024 + nn] = f2bf(acc);
}

// ---------------------------------------------------------------- GEMM (256^2, 8-phase T3+T4 schedule)
// Shared machinery for k_gemm256 (Wpost) and k_gemm_qkv (fused QKV, N=3072).
// BM=BN=256, BK=64. 512 threads = 8 waves (2M x 4N), per-wave 128x64 output.
// LDS 128 KiB: 2 dbuf x {A 256x64, B 256x64} bf16; granule swizzle g^=(row&7) on both
// stage-source and ds_read (rule 21). 8 phases per 2 K-tiles; counted vmcnt(8)/(6) at
// phases 1,3,5,7; vmcnt reaches 0 only in the peeled final iteration (schedule
// harness-verified in round 3).
// Audit (round 4->5): B-row max n0+rbB1+32=3071<3072; A-row max 38399; LDS dest max
// 32752<32768; swizzle bijective for grid%8==0; barriers uniform across all 512 threads.

#define VMCNT(n) do { asm volatile("s_waitcnt vmcnt(" #n ")" ::: "memory"); \
                      __builtin_amdgcn_sched_barrier(0); } while (0)
#define BARF() do { asm volatile("" ::: "memory"); __builtin_amdgcn_s_barrier(); asm volatile("" ::: "memory"); } while (0)
#define GLD(SRC, DST) __builtin_amdgcn_global_load_lds((const AS_GLOBAL u16*)(SRC), (AS_LDS u16*)(DST), 16, 0, 0)
#define LDSA(d) ((AS_LDS char*)&lds[d][0][0])
#define LDSB(d) ((AS_LDS char*)&lds[d][1][0])

#define STAGE_A(d, h, t) do {                                                   \
  GLD(sA0 + (((size_t)(h)) << 6) * K + ((t) << 6), LDSA(d) + dA0 + ((h) << 13)); \
  GLD(sA1 + (((size_t)(h)) << 6) * K + ((t) << 6), LDSA(d) + dA1 + ((h) << 13)); \
} while (0)
#define STAGE_B(d, h, t) do {                                                   \
  GLD(sB0 + (((size_t)(h)) << 5) * K + ((t) << 6), LDSB(d) + dB0 + ((h) << 12)); \
  GLD(sB1 + (((size_t)(h)) << 5) * K + ((t) << 6), LDSB(d) + dB1 + ((h) << 12)); \
} while (0)

#define LOAD_A(d, qm) do {                                                       \
  _Pragma("unroll") for (int mi_ = 0; mi_ < 4; ++mi_) {                          \
    af[mi_][0] = *(const bf16x8*)&lds[d][0][abase + (((qm)*64 + mi_*16) << 6) + gk0]; \
    af[mi_][1] = *(const bf16x8*)&lds[d][0][abase + (((qm)*64 + mi_*16) << 6) + gk1]; \
  } } while (0)
#define LOAD_B(d, qn) do {                                                       \
  _Pragma("unroll") for (int ni_ = 0; ni_ < 2; ++ni_) {                          \
    bfb[ni_][0] = *(const bf16x8*)&lds[d][1][bbase + (((qn)*32 + ni_*16) << 6) + gk0]; \
    bfb[ni_][1] = *(const bf16x8*)&lds[d][1][bbase + (((qn)*32 + ni_*16) << 6) + gk1]; \
  } } while (0)
#define MFMA16(qm, qn) do {                                                      \
  __builtin_amdgcn_s_setprio(1);                                                 \
  _Pragma("unroll") for (int mi_ = 0; mi_ < 4; ++mi_)                            \
  _Pragma("unroll") for (int ni_ = 0; ni_ < 2; ++ni_) {                          \
    acc[(qm)*4+mi_][(qn)*2+ni_] = __builtin_amdgcn_mfma_f32_16x16x32_bf16(       \
        af[mi_][0], bfb[ni_][0], acc[(qm)*4+mi_][(qn)*2+ni_], 0, 0, 0);          \
    acc[(qm)*4+mi_][(qn)*2+ni_] = __builtin_amdgcn_mfma_f32_16x16x32_bf16(       \
        af[mi_][1], bfb[ni_][1], acc[(qm)*4+mi_][(qn)*2+ni_], 0, 0, 0);          \
  }                                                                              \
  __builtin_amdgcn_s_setprio(0); } while (0)

// The full verified pipeline (prologue + steady loop + peeled tail), as a macro so the
// fused-QKV kernel and the Wpost kernel share it exactly.
#define GEMM_MAINLOOP()                                                          \
  STAGE_B(0, 0, 0);  STAGE_A(0, 1, 0);  STAGE_A(0, 0, 0);  STAGE_B(0, 1, 0);     \
  STAGE_B(1, 0, 1);  STAGE_A(1, 1, 1);                                           \
  VMCNT(6);  BARF();                                                             \
  const int nk = K >> 6;                                                         \
  for (int i = 0; i < (nk >> 1) - 1; ++i) {                                      \
    const int t1 = 2 * i + 1, t2 = 2 * i + 2, t3 = 2 * i + 3;                    \
    LOAD_A(0, 0); LOAD_B(0, 0);                                                  \
    STAGE_A(1, 0, t1);                                                           \
    BARF(); MFMA16(0, 0); BARF();                                                \
    LOAD_A(0, 1);                                                                \
    STAGE_B(1, 1, t1);                                                           \
    BARF(); MFMA16(1, 0); VMCNT(8); BARF();                                      \
    LOAD_B(0, 1);                                                                \
    STAGE_B(0, 0, t2);                                                           \
    BARF(); MFMA16(1, 1); BARF();                                                \
    LOAD_A(0, 0);                                                                \
    STAGE_A(0, 1, t2);                                                           \
    BARF(); MFMA16(0, 1); VMCNT(6); BARF();                                      \
    LOAD_A(1, 0); LOAD_B(1, 0);                                                  \
    STAGE_A(0, 0, t2);                                                           \
    BARF(); MFMA16(0, 0); BARF();                                                \
    LOAD_A(1, 1);                                                                \
    STAGE_B(0, 1, t2);                                                           \
    BARF(); MFMA16(1, 0); VMCNT(8); BARF();                                      \
    LOAD_B(1, 1);                                                                \
    STAGE_B(1, 0, t3);                                                           \
    BARF(); MFMA16(1, 1); BARF();                                                \
    LOAD_A(1, 0);                                                                \
    STAGE_A(1, 1, t3);                                                           \
    BARF(); MFMA16(0, 1); VMCNT(6); BARF();                                      \
  }                                                                              \
  {                                                                              \
    const int t1 = nk - 1;                                                       \
    LOAD_A(0, 0); LOAD_B(0, 0);                                                  \
    STAGE_A(1, 0, t1);                                                           \
    BARF(); MFMA16(0, 0); BARF();                                                \
    LOAD_A(0, 1);                                                                \
    STAGE_B(1, 1, t1);                                                           \
    BARF(); MFMA16(1, 0); VMCNT(8); BARF();                                      \
    LOAD_B(0, 1);                                                                \
    BARF(); MFMA16(1, 1); BARF();                                                \
    LOAD_A(0, 0);                                                                \
    BARF(); MFMA16(0, 1); VMCNT(2); BARF();                                      \
    LOAD_A(1, 0); LOAD_B(1, 0);                                                  \
    BARF(); MFMA16(0, 0); BARF();                                                \
    LOAD_A(1, 1);                                                                \
    BARF(); MFMA16(1, 0); VMCNT(0); BARF();                                      \
    LOAD_B(1, 1);                                                                \
    BARF(); MFMA16(1, 1); BARF();                                                \
    LOAD_A(1, 0);                                                                \
    BARF(); MFMA16(0, 1);                                                        \
  }

// Common per-thread setup (indices, staging pointers, acc init).
#define GEMM_SETUP(NTN)                                                          \
  __shared__ __align__(16) u16 lds[2][2][16384];                                 \
  const int tid = threadIdx.x;                                                   \
  const int wave = tid >> 6, lane = tid & 63;                                    \
  const int l16 = lane & 15, quad = lane >> 4;                                   \
  const int wm = wave >> 2, wn = wave & 3;                                       \
  const int q8 = (int)gridDim.x >> 3;                                            \
  const int wg = ((int)blockIdx.x & 7) * q8 + ((int)blockIdx.x >> 3);            \
  const int m0 = (wg / (NTN)) << 8;                                              \
  const int n0 = (wg % (NTN)) << 8;                                              \
  const int sx = l16 & 7;                                                        \
  const int gk0 = (quad ^ sx) << 3;                                              \
  const int gk1 = ((4 + quad) ^ sx) << 3;                                        \
  const int abase = (wm * 128 + l16) << 6;                                       \
  const int bbase = (wn * 64 + l16) << 6;                                        \
  const int rl0 = tid >> 3, g0 = tid & 7;                                        \
  const int rl1 = rl0 + 64;                                                      \
  const int swz0 = (g0 ^ (rl0 & 7)) << 3;                                        \
  const int rbA0 = ((rl0 >> 6) << 7) + (rl0 & 63);                               \
  const int rbA1 = ((rl1 >> 6) << 7) + (rl1 & 63);                               \
  const int rbB0 = ((rl0 >> 5) << 6) + (rl0 & 31);                               \
  const int rbB1 = ((rl1 >> 5) << 6) + (rl1 & 31);                               \
  const u16* sA0 = A + (size_t)(m0 + rbA0) * K + swz0;                           \
  const u16* sA1 = A + (size_t)(m0 + rbA1) * K + swz0;                           \
  const u16* sB0 = Bt + (size_t)(n0 + rbB0) * K + swz0;                          \
  const u16* sB1 = Bt + (size_t)(n0 + rbB1) * K + swz0;                          \
  const int dA0 = (rbA0 << 7) + (g0 << 4);                                       \
  const int dA1 = (rbA1 << 7) + (g0 << 4);                                       \
  const int dB0 = (rbB0 << 7) + (g0 << 4);                                       \
  const int dB1 = (rbB1 << 7) + (g0 << 4);                                       \
  f32x4 acc[8][4];                                                               \
  _Pragma("unroll") for (int i = 0; i < 8; ++i)                                  \
    _Pragma("unroll") for (int j = 0; j < 4; ++j) {                              \
      f32x4 z = {0.f, 0.f, 0.f, 0.f};                                            \
      acc[i][j] = z;                                                             \
    }                                                                            \
  bf16x8 af[4][2], bfb[2][2];

// ---- Wpost GEMM: C fp32 row-major [M][N]
__global__ __launch_bounds__(512, 2) void k_gemm256(
    const u16* __restrict__ A, const u16* __restrict__ Bt, float* __restrict__ Cout,
    int M, int N, int K) {
  GEMM_SETUP(N >> 8)
  GEMM_MAINLOOP()
  const int mb = m0 + wm * 128, nb = n0 + wn * 64;
  #pragma unroll
  for (int ni = 0; ni < 4; ++ni) {
    int col = nb + ni * 16 + l16;
    #pragma unroll
    for (int mi = 0; mi < 8; ++mi) {
      int row = mb + mi * 16 + quad * 4;
      #pragma unroll
      for (int r = 0; r < 4; ++r)
        Cout[(size_t)(row + r) * N + col] = acc[mi][ni][r];
    }
  }
}

// ---- Fused QKV GEMM: Bt = wqt (wqt|wkt|wvt contiguous, N=3072). Section by n0:
//   sec 0 -> Q bf16 [M][1024] * qsc[col];  sec 1 -> K bf16 [M][1024] * ks;
//   sec 2 -> V bf16 TRANSPOSED Vt[col*M + row].
__global__ __launch_bounds__(512, 2) void k_gemm_qkv(
    const u16* __restrict__ A, const u16* __restrict__ Bt,
    u16* __restrict__ Qo, u16* __restrict__ Ko, u16* __restrict__ Vt,
    const float* __restrict__ qsc, float ks, int M, int K) {
  GEMM_SETUP(12)
  GEMM_MAINLOOP()
  const int sec = n0 >> 10;
  const int mb = m0 + wm * 128;
  const int nbl = (n0 & 1023) + wn * 64;
  if (sec == 2) {
    #pragma unroll
    for (int ni = 0; ni < 4; ++ni) {
      int col = nbl + ni * 16 + l16;
      #pragma unroll
      for (int mi = 0; mi < 8; ++mi) {
        int row = mb + mi * 16 + quad * 4;
        ushort4 o;
        o.x = f2bf(acc[mi][ni][0]);
        o.y = f2bf(acc[mi][ni][1]);
        o.z = f2bf(acc[mi][ni][2]);
        o.w = f2bf(acc[mi][ni][3]);
        *(ushort4*)&Vt[(size_t)col * M + row] = o;
      }
    }
  } else {
    u16* Out = (sec == 0) ? Qo : Ko;
    #pragma unroll
    for (int ni = 0; ni < 4; ++ni) {
      int col = nbl + ni * 16 + l16;
      float cs = (sec == 0) ? qsc[col] : ks;
      #pragma unroll
      for (int mi = 0; mi < 8; ++mi) {
        int row = mb + mi * 16 + quad * 4;
        #pragma unroll
        for (int r = 0; r < 4; ++r)
          Out[(size_t)(row + r) * 1024 + col] = f2bf(acc[mi][ni][r] * cs);
      }
    }
  }
}

#undef GEMM_SETUP
#undef GEMM_MAINLOOP
#undef STAGE_A
#undef STAGE_B
#undef LOAD_A
#undef LOAD_B
#undef MFMA16

// ---------------------------------------------------------------- attention (MFMA, persistent)
// unit = (b, n, h); CHUNK=12, PAST=12, CTX=24, P=25, D=128, SOFTCAP=50.
// q,k: [b*2400+s][1024] bf16 rows.  vt: TRANSPOSED [col][38400] bf16 (col = h*128+d), +16 u16 front slack.
// relkb: [32][1024] bf16 (rows 25..31 garbage, never used in output).
// C-layout: col = l16, row = quad*4+reg.  A-layout: A[m=l16][k=quad*8+j].
// Persistent: grid 2048 blocks (8/CU resident), each wave grid-strides over units.
// No barriers in the loop (LDS strictly per-wave; per-wave DS ops are in-order).
__global__ __launch_bounds__(256) void k_attn_mfma(
    const u16* __restrict__ q, const u16* __restrict__ k, const u16* __restrict__ vt,
    const u16* __restrict__ relkb, u16* __restrict__ ctx) {
  __shared__ float bdm_s[4][400];     // per-wave [16][25] row-major (flat reindex target)
  __shared__ u16 attnb[4][16 * 32];   // per-wave P matrix, A-layout staging

  const int tid = threadIdx.x;
  const int w = tid >> 6, lane = tid & 63;
  const int l16 = lane & 15, quad = lane >> 4;

  for (int id0 = (int)blockIdx.x * 4; id0 < 25600; id0 += (int)gridDim.x * 4) {
    const int id = id0 + w;                   // 0..25599
    const int b = id / 1600;
    const int rr = id % 1600;
    const int n = rr >> 3, h = rr & 7;
    const int s0 = n * 12;
    const size_t rowbase = (size_t)b * 2400;

    // ---- Q a-frags (m = l16 = q-row, k-chunks c: k = 32c + quad*8 + j)
    bf16x8 qf[4];
    {
      int sq = s0 + l16;
      if (sq > 2399) sq = 2399;  // pad q-rows read real data; outputs never stored
      const u16* qp = q + ((rowbase + sq) * 1024 + (size_t)h * 128 + quad * 8);
      #pragma unroll
      for (int c = 0; c < 4; ++c) qf[c] = *(const bf16x8*)(qp + 32 * c);
    }

    // ---- bd = Q @ rel_k^T  (2 p-tiles), store to LDS [16][25] for flat reindex
    #pragma unroll
    for (int pt = 0; pt < 2; ++pt) {
      int p = pt * 16 + l16;
      const u16* rp = relkb + ((size_t)p * 1024 + (size_t)h * 128 + quad * 8);
      f32x4 acc = {0.f, 0.f, 0.f, 0.f};
      #pragma unroll
      for (int c = 0; c < 4; ++c)
        acc = __builtin_amdgcn_mfma_f32_16x16x32_bf16(qf[c], *(const bf16x8*)(rp + 32 * c), acc, 0, 0, 0);
      if (p < 25) {
        #pragma unroll
        for (int r = 0; r < 4; ++r)
          bdm_s[w][(quad * 4 + r) * 25 + p] = acc[r];
      }
    }
    __threadfence_block();  // LDS write->read ordering within wave

    // ---- ac = Q @ K^T (2 t-tiles) + combine with shifted bd + softcap
    float l0[4], l1[4];
    #pragma unroll
    for (int kt = 0; kt < 2; ++kt) {
      int t = kt * 16 + l16;
      int sk = s0 - 12 + t;
      bool kvalid = ((unsigned)sk < 2400u);
      int ska = kvalid ? sk : 0;
      const u16* kp = k + ((rowbase + ska) * 1024 + (size_t)h * 128 + quad * 8);
      short km = kvalid ? (short)0xFFFF : (short)0;
      bf16x8 kmv = {km, km, km, km, km, km, km, km};
      f32x4 acc = {0.f, 0.f, 0.f, 0.f};
      #pragma unroll
      for (int c = 0; c < 4; ++c) {
        bf16x8 kf = *(const bf16x8*)(kp + 32 * c);
        kf &= kmv;  // zero-padded context rows: ac = 0, bd still enters softmax
        acc = __builtin_amdgcn_mfma_f32_16x16x32_bf16(qf[c], kf, acc, 0, 0, 0);
      }
      #pragma unroll
      for (int r = 0; r < 4; ++r) {
        float bd = bdm_s[w][(quad * 4 + r) * 24 + t];  // rel-shift = flat reindex
        float lg = tanhf((acc[r] + bd) * (1.0f / 50.0f)) * 50.0f;
        if (kt == 1 && l16 >= 8) lg = -INFINITY;  // t >= 24: outside CTX
        if (kt) l1[r] = lg; else l0[r] = lg;
      }
    }

    // ---- softmax over t (row q = quad*4+r lives in a 16-lane group)
    float at0[4], at1[4];
    #pragma unroll
    for (int r = 0; r < 4; ++r) {
      float m = fmaxf(l0[r], l1[r]);
      #pragma unroll
      for (int s = 1; s < 16; s <<= 1) m = fmaxf(m, __shfl_xor(m, s, 64));
      float e0 = __expf(l0[r] - m), e1 = __expf(l1[r] - m);
      float sum = e0 + e1;
      #pragma unroll
      for (int s = 1; s < 16; s <<= 1) sum += __shfl_xor(sum, s, 64);
      float inv = 1.0f / sum;
      at0[r] = e0 * inv;
      at1[r] = e1 * inv;
    }

    // ---- P: C-layout -> A-layout via LDS (bf16)
    #pragma unroll
    for (int r = 0; r < 4; ++r) {
      attnb[w][(quad * 4 + r) * 32 + l16] = f2bf(at0[r]);
      attnb[w][(quad * 4 + r) * 32 + 16 + l16] = f2bf(at1[r]);
    }
    __threadfence_block();
    bf16x8 paf = *(const bf16x8*)&attnb[w][l16 * 32 + quad * 8];

    // ---- PV: 8 d-tiles, B-frag = V^T[d][t] contiguous in vt; mask invalid s elements
    int slo = s0 - 12 + quad * 8;
    bf16x8 vmsk;
    #pragma unroll
    for (int j = 0; j < 8; ++j)
      vmsk[j] = ((unsigned)(slo + j) < 2400u) ? (short)0xFFFF : (short)0;

    f32x4 oacc[8];
    #pragma unroll
    for (int dt = 0; dt < 8; ++dt) {
      int col = h * 128 + dt * 16 + l16;
      const u16* vp = vt + ((size_t)col * 38400 + (long)(rowbase + s0 - 12 + quad * 8));
      ushort4 va = *(const ushort4*)vp;
      ushort4 vb = *(const ushort4*)(vp + 4);
      bf16x8 vf = {(short)va.x, (short)va.y, (short)va.z, (short)va.w,
                   (short)vb.x, (short)vb.y, (short)vb.z, (short)vb.w};
      vf &= vmsk;
      f32x4 z = {0.f, 0.f, 0.f, 0.f};
      oacc[dt] = __builtin_amdgcn_mfma_f32_16x16x32_bf16(paf, vf, z, 0, 0, 0);
    }

    // ---- store O (rows q = quad*4+r, only q<12 valid -> quads 0..2)
    if (quad < 3) {
      #pragma unroll
      for (int dt = 0; dt < 8; ++dt) {
        int col = h * 128 + dt * 16 + l16;
        #pragma unroll
        for (int r = 0; r < 4; ++r) {
          int qi = quad * 4 + r;
          ctx[(rowbase + s0 + qi) * 1024 + col] = f2bf(oacc[dt][r]);
        }
      }
    }
  }
}

// ---------------------------------------------------------------- launch

extern "C" void kernel_launch(void* const* d_in, const int* in_sizes, int n_in,
                              void* d_out, int out_size, void* d_ws, size_t ws_size,
                              hipStream_t stream) {
  const float* x       = (const float*)d_in[0];  // [16,2400,1024]
  const float* pos_emb = (const float*)d_in[1];  // [25,1024]
  const float* Wq      = (const float*)d_in[2];
  const float* Wk      = (const float*)d_in[3];
  const float* Wv      = (const float*)d_in[4];
  const float* Wpost   = (const float*)d_in[5];
  const float* Wrel    = (const float*)d_in[6];
  const float* pds     = (const float*)d_in[7];  // [128]
  float* out = (float*)d_out;

  const int M = 38400, HS = 1024;           // M = B*S = 16*2400
  const size_t XE = (size_t)M * HS;

  // workspace layout (u16 units)
  u16* xbf = (u16*)d_ws;                 // XE; reused as ctx after QKV GEMMs consume it
  u16* qbf = xbf + XE;                   // XE
  u16* kbf = qbf + XE;                   // XE
  u16* vt_alloc = kbf + XE;              // XE + 64 (slack for boundary-masked loads)
  u16* vt = vt_alloc + 16;
  u16* wqt = vt_alloc + XE + 64;         // wqt|wkt|wvt contiguous -> fused QKV Bt
  u16* wkt = wqt + (size_t)HS * HS;
  u16* wvt = wkt + (size_t)HS * HS;
  u16* wrt = wvt + (size_t)HS * HS;
  u16* wpt = wrt + (size_t)HS * HS;
  u16* relkb = wpt + (size_t)HS * HS;    // 32*1024 (rows 25..31 unwritten, harmless)
  float* qsc = (float*)(relkb + 32 * 1024);

  const double LN2 = 0.6931471805599453;
  const float QS = (float)((1.0 / sqrt(128.0)) / LN2);
  const float KS = (float)(log(1.0 + exp(1.0)) / LN2);

  // 1) x -> bf16
  k_f32_to_bf16<<<(int)(XE / 4 / 256), 256, 0, stream>>>(x, xbf, (int)(XE / 4));
  // 2) transpose weights -> bf16 [n][k]
  dim3 tg(32, 32);
  k_transpose_w<<<tg, 256, 0, stream>>>(Wq, wqt);
  k_transpose_w<<<tg, 256, 0, stream>>>(Wk, wkt);
  k_transpose_w<<<tg, 256, 0, stream>>>(Wv, wvt);
  k_transpose_w<<<tg, 256, 0, stream>>>(Wrel, wrt);
  k_transpose_w<<<tg, 256, 0, stream>>>(Wpost, wpt);
  // 3) per-column q scale
  k_qscale<<<4, 256, 0, stream>>>(pds, qsc, QS);
  // 4) rel_k = pos_emb @ Wrel -> bf16
  k_relk<<<dim3(4, 25), 256, 0, stream>>>(pos_emb, wrt, relkb);
  // 5) fused QKV projection: Bt = [wqt|wkt|wvt], N=3072, grid = 150*12 = 1800 (%8==0)
  k_gemm_qkv<<<(M / 256) * 12, 512, 0, stream>>>(xbf, wqt, qbf, kbf, vt, qsc, KS, M, HS);
  // 6) attention -> ctx (persistent, 2048 blocks; reuses xbf region)
  k_attn_mfma<<<2048, 256, 0, stream>>>(qbf, kbf, vt, relkb, xbf);
  // 7) out = ctx @ Wpost (fp32 out), grid = 150*4 = 600
  k_gemm256<<<(M / 256) * (HS / 256), 512, 0, stream>>>(xbf, wpt, out, M, HS, HS);
}